// Round 9
// baseline (180.017 us; speedup 1.0000x reference)
//
#include <hip/hip_runtime.h>
#include <hip/hip_bf16.h>
#include <hip/hip_fp16.h>
#include <math.h>

#define NN 50000
#define NE 500000
#define IC 128
#define OC 256
#define NPAD 50176            // 196 * 256
#define NEB 1954              // edge blocks = ceil(NE/256)
#define CAP 64                // CSR bucket capacity per node (Poisson(10) edges/node)

typedef short bf16x8 __attribute__((ext_vector_type(8)));
typedef float f32x4 __attribute__((ext_vector_type(4)));

static __device__ inline unsigned short f2b(float f) {
    __hip_bfloat16 h = __float2bfloat16(f);   // RNE
    return *reinterpret_cast<unsigned short*>(&h);
}
static __device__ inline float b2f(short u) {
    unsigned v = ((unsigned)(unsigned short)u) << 16;
    return __int_as_float(v);
}
static __device__ inline float h2f(unsigned short h) {
    __half v = __ushort_as_half(h);
    return __half2float(v);
}
// deg64 low 32 = sum(sigmoid(w)) in 8.24 fixed (EXCLUDING self-loop; buffer is
// memset-0), high 32 = edge count. Same decode everywhere -> bit-identical di.
static __device__ inline float deg_to_di(unsigned long long dv) {
    return rsqrtf((float)(unsigned)dv * (1.0f / 16777216.0f) + 1.0f);
}

// ---------------- pass1: single u64 atomic (count|degfix) returns ordinal;
//                  scatter epack[c*CAP+ord] = (w:fp16 | row:u16);
//                  fused W->WT bf16 conversion ----------------
__global__ void k_pass1(const int* __restrict__ row,
                        const int* __restrict__ col,
                        const float* __restrict__ ew,
                        unsigned long long* __restrict__ deg64,
                        unsigned* __restrict__ epack,
                        const float* __restrict__ W,
                        unsigned short* __restrict__ WT) {
    int g = blockIdx.x * 256 + threadIdx.x;
    if (g < NE) {
        int c = col[g];
        float w = 1.0f / (1.0f + expf(-ew[g]));   // sigmoid
        unsigned long long pack = (1ull << 32) | (unsigned long long)(unsigned)(w * 16777216.0f);
        unsigned long long old = atomicAdd(&deg64[c], pack);
        int ord = (int)(old >> 32);               // within-bucket ordinal
        if (ord < CAP) {                          // safety clamp (never hit for this data)
            unsigned short wh = __half_as_ushort(__float2half_rn(w));
            unsigned p = ((unsigned)wh << 16) | (unsigned)row[g];   // row < 65536
            epack[(size_t)c * CAP + ord] = p;
        }
    }
    // fused W -> W^T bf16
    if (g < IC * OC) {
        int k = g >> 8;
        int n = g & 255;
        WT[n * IC + k] = f2b(W[g]);
    }
}

// ---------------- scale: xb[n] = bf16(x[n] * rsqrt(deg[n])) ----------------
// Pre-scaling by the SOURCE-side dinv removes the per-edge random dinv[r]
// load (and one dependency hop) from the latency-bound gather.
__global__ __launch_bounds__(256) void k_scale(
        const unsigned long long* __restrict__ deg64,
        const float* __restrict__ x,
        unsigned short* __restrict__ xb) {
    int t = threadIdx.x;
    int n = blockIdx.x * 16 + (t >> 4);       // n < 50000 always (3125*16 exact)
    int l = t & 15;
    float di = deg_to_di(deg64[n]);
    const float4* xr = (const float4*)(x + (size_t)n * IC + l * 8);
    float4 a0 = xr[0], a1 = xr[1];
    bf16x8 o;
    o[0] = (short)f2b(a0.x * di); o[1] = (short)f2b(a0.y * di);
    o[2] = (short)f2b(a0.z * di); o[3] = (short)f2b(a0.w * di);
    o[4] = (short)f2b(a1.x * di); o[5] = (short)f2b(a1.y * di);
    o[6] = (short)f2b(a1.z * di); o[7] = (short)f2b(a1.w * di);
    ((bf16x8*)xb)[(size_t)n * 16 + l] = o;
}

// ---------------- fused gather + GEMM (r4 inner loop, 128-thread blocks) ----------------
// 16 nodes per block, 8 lanes per node, 2 waves/block, grid 3125 (exact).
// Identical per-lane work to r4 but 2.6x more independent blocks per CU
// (16 blocks/CU VGPR-capped vs 6.1) -> more outstanding scattered sectors
// (Little's law). uint4 descriptor prefetch + unroll-4: 8 independent 16B
// row loads in flight per lane. Phase B: 2 waves, each 16m x 128n in two
// 64n chunks (wf[4]/acc4[4] register reuse keeps VGPR <= 64).
__global__ __launch_bounds__(128, 8) void k_gather_gemm(
        const unsigned short* __restrict__ xb,
        const unsigned long long* __restrict__ deg64,
        const unsigned* __restrict__ epack,
        const unsigned short* __restrict__ WT,
        const float* __restrict__ bias,
        float* __restrict__ out) {
    __shared__ __align__(16) unsigned short a[16][136];   // 272B stride: 2-way alias only (free)

    const int base = blockIdx.x * 16;
    const int g = threadIdx.x >> 3;           // node group 0..15
    const int l8 = threadIdx.x & 7;           // owns segments l8 and l8+8 (8 bf16 each)
    const int n = base + g;                   // always < 50000 (3125*16 exact)
    const bf16x8* xv = (const bf16x8*)xb;     // row = 16 units of 8 bf16

    unsigned long long dv = deg64[n];
    float di = deg_to_di(dv);
    int cnt = (int)(dv >> 32);
    if (cnt > CAP) cnt = CAP;

    // self term: xb[n] = x[n]*di, want x[n]*di^2 -> scale by di
    bf16x8 xs0 = xv[(size_t)n * 16 + l8];
    bf16x8 xs1 = xv[(size_t)n * 16 + 8 + l8];
    float acc[16];
    #pragma unroll
    for (int c = 0; c < 8; ++c) { acc[c] = b2f(xs0[c]) * di; acc[8 + c] = b2f(xs1[c]) * di; }

    const unsigned* ep = epack + (size_t)n * CAP;
    uint4 q = *(const uint4*)ep;              // descriptors for group 0
    int e = 0;
    for (; e + 4 <= cnt; e += 4) {
        uint4 cur = q;
        q = *(const uint4*)(ep + e + 4);      // prefetch next group (overread safe: pad)
        int r0 = (int)(cur.x & 0xFFFFu);
        int r1 = (int)(cur.y & 0xFFFFu);
        int r2 = (int)(cur.z & 0xFFFFu);
        int r3 = (int)(cur.w & 0xFFFFu);
        float w0 = h2f((unsigned short)(cur.x >> 16)) * di;
        float w1 = h2f((unsigned short)(cur.y >> 16)) * di;
        float w2 = h2f((unsigned short)(cur.z >> 16)) * di;
        float w3 = h2f((unsigned short)(cur.w >> 16)) * di;
        bf16x8 v00 = xv[(size_t)r0 * 16 + l8];
        bf16x8 v01 = xv[(size_t)r0 * 16 + 8 + l8];
        bf16x8 v10 = xv[(size_t)r1 * 16 + l8];
        bf16x8 v11 = xv[(size_t)r1 * 16 + 8 + l8];
        bf16x8 v20 = xv[(size_t)r2 * 16 + l8];
        bf16x8 v21 = xv[(size_t)r2 * 16 + 8 + l8];
        bf16x8 v30 = xv[(size_t)r3 * 16 + l8];
        bf16x8 v31 = xv[(size_t)r3 * 16 + 8 + l8];
        #pragma unroll
        for (int c = 0; c < 8; ++c) { acc[c] += b2f(v00[c]) * w0; acc[8 + c] += b2f(v01[c]) * w0; }
        #pragma unroll
        for (int c = 0; c < 8; ++c) { acc[c] += b2f(v10[c]) * w1; acc[8 + c] += b2f(v11[c]) * w1; }
        #pragma unroll
        for (int c = 0; c < 8; ++c) { acc[c] += b2f(v20[c]) * w2; acc[8 + c] += b2f(v21[c]) * w2; }
        #pragma unroll
        for (int c = 0; c < 8; ++c) { acc[c] += b2f(v30[c]) * w3; acc[8 + c] += b2f(v31[c]) * w3; }
    }
    for (; e < cnt; ++e) {                    // tail 0-3 edges, lines already hot
        unsigned p = ep[e];
        int r = (int)(p & 0xFFFFu);
        float w = h2f((unsigned short)(p >> 16)) * di;
        bf16x8 v0 = xv[(size_t)r * 16 + l8];
        bf16x8 v1 = xv[(size_t)r * 16 + 8 + l8];
        #pragma unroll
        for (int c = 0; c < 8; ++c) { acc[c] += b2f(v0[c]) * w; acc[8 + c] += b2f(v1[c]) * w; }
    }

    bf16x8 o0, o1;
    #pragma unroll
    for (int c = 0; c < 8; ++c) { o0[c] = (short)f2b(acc[c]); o1[c] = (short)f2b(acc[8 + c]); }
    *(bf16x8*)(&a[g][l8 * 8]) = o0;
    *(bf16x8*)(&a[g][64 + l8 * 8]) = o1;

    __syncthreads();

    // --- Phase B: GEMM  out[16m x 256n] = a @ WT^T + bias; 2 waves x 128n ---
    const int w = threadIdx.x >> 6;           // wave 0..1 -> n-half
    const int lane = threadIdx.x & 63;
    const int lm = lane & 15;
    const int lk = (lane >> 4) * 8;
    const int mcol = lane & 15;
    const int nb4 = (lane >> 4) * 4;
    const int m = base + mcol;                // always < 50000

    #pragma unroll
    for (int ch = 0; ch < 2; ++ch) {          // two 64n chunks, reuse wf/acc regs
        const int n0 = w * 128 + ch * 64;
        f32x4 acc4[4] = {};
        #pragma unroll
        for (int ks = 0; ks < 4; ++ks) {
            const int k0 = ks * 32 + lk;
            bf16x8 wf[4];
            #pragma unroll
            for (int j = 0; j < 4; ++j)
                wf[j] = *(const bf16x8*)(WT + (size_t)(n0 + j * 16 + lm) * IC + k0);
            bf16x8 af = *(const bf16x8*)(&a[lm][k0]);
            #pragma unroll
            for (int j = 0; j < 4; ++j)
                acc4[j] = __builtin_amdgcn_mfma_f32_16x16x32_bf16(wf[j], af, acc4[j], 0, 0, 0);
        }
        // swapped D layout: col(lane&15) = m-dim, row((lane>>4)*4+reg) = n-dim
        #pragma unroll
        for (int j = 0; j < 4; ++j) {
            int nn = n0 + j * 16 + nb4;
            float4 bv = *(const float4*)&bias[nn];
            float4 ov;
            ov.x = acc4[j][0] + bv.x;
            ov.y = acc4[j][1] + bv.y;
            ov.z = acc4[j][2] + bv.z;
            ov.w = acc4[j][3] + bv.w;
            *(float4*)(out + (size_t)m * OC + nn) = ov;
        }
    }
}

// ---------------- launch ----------------
extern "C" void kernel_launch(void* const* d_in, const int* in_sizes, int n_in,
                              void* d_out, int out_size, void* d_ws, size_t ws_size,
                              hipStream_t stream) {
    const float* x  = (const float*)d_in[0];
    const float* W  = (const float*)d_in[1];
    const float* b  = (const float*)d_in[2];
    const int*   ei = (const int*)d_in[3];
    const float* ew = (const float*)d_in[4];
    const int* row = ei;            // source
    const int* col = ei + NE;       // target
    float* out = (float*)d_out;

    char* w0 = (char*)d_ws;
    unsigned long long* deg64 = (unsigned long long*)w0;  w0 += NPAD * 8;
    unsigned* epack = (unsigned*)w0;             w0 += ((size_t)NPAD * CAP + 128) * 4;  // 12.9 MB + pad
    unsigned short* WT   = (unsigned short*)w0;  w0 += IC * OC * 2;
    unsigned short* xb   = (unsigned short*)w0;  // NN*IC bf16 = 12.8 MB (pre-scaled by dinv)

    hipMemsetAsync(deg64, 0, NPAD * 8, stream);   // deg = self-loop-excluded 0; +1.0 in decode
    k_pass1      <<<NEB, 256, 0, stream>>>(row, col, ew, deg64, epack, W, WT);
    k_scale      <<<NN / 16, 256, 0, stream>>>(deg64, x, xb);
    k_gather_gemm<<<NN / 16, 128, 0, stream>>>(xb, deg64, epack, WT, b, out);
}

// Round 10
// 160.495 us; speedup vs baseline: 1.1216x; 1.1216x over previous
//
#include <hip/hip_runtime.h>
#include <hip/hip_bf16.h>
#include <hip/hip_fp16.h>
#include <math.h>

#define NN 50000
#define NE 500000
#define IC 128
#define OC 256
#define NPAD 50176            // 196 * 256
#define NEB 1954              // edge blocks = ceil(NE/256)
#define CAP 64                // CSR bucket capacity per node (Poisson(10) edges/node)

typedef short bf16x8 __attribute__((ext_vector_type(8)));
typedef float f32x4 __attribute__((ext_vector_type(4)));

static __device__ inline unsigned short f2b(float f) {
    __hip_bfloat16 h = __float2bfloat16(f);   // RNE
    return *reinterpret_cast<unsigned short*>(&h);
}
static __device__ inline float b2f(short u) {
    unsigned v = ((unsigned)(unsigned short)u) << 16;
    return __int_as_float(v);
}
static __device__ inline float h2f(unsigned short h) {
    __half v = __ushort_as_half(h);
    return __half2float(v);
}
// deg64 low 32 = sum(sigmoid(w)) in 8.24 fixed (EXCLUDING self-loop; buffer is
// memset-0), high 32 = edge count. Same decode everywhere -> bit-identical di.
static __device__ inline float deg_to_di(unsigned long long dv) {
    return rsqrtf((float)(unsigned)dv * (1.0f / 16777216.0f) + 1.0f);
}

// ---------------- pass1: single u64 atomic (count|degfix) returns ordinal;
//                  scatter epack[c*CAP+ord] = (w:fp16 | row:u16);
//                  fused W->WT bf16 conversion ----------------
__global__ void k_pass1(const int* __restrict__ row,
                        const int* __restrict__ col,
                        const float* __restrict__ ew,
                        unsigned long long* __restrict__ deg64,
                        unsigned* __restrict__ epack,
                        const float* __restrict__ W,
                        unsigned short* __restrict__ WT) {
    int g = blockIdx.x * 256 + threadIdx.x;
    if (g < NE) {
        int c = col[g];
        float w = 1.0f / (1.0f + expf(-ew[g]));   // sigmoid
        unsigned long long pack = (1ull << 32) | (unsigned long long)(unsigned)(w * 16777216.0f);
        unsigned long long old = atomicAdd(&deg64[c], pack);
        int ord = (int)(old >> 32);               // within-bucket ordinal
        if (ord < CAP) {                          // safety clamp (never hit for this data)
            unsigned short wh = __half_as_ushort(__float2half_rn(w));
            unsigned p = ((unsigned)wh << 16) | (unsigned)row[g];   // row < 65536
            epack[(size_t)c * CAP + ord] = p;
        }
    }
    // fused W -> W^T bf16
    if (g < IC * OC) {
        int k = g >> 8;
        int n = g & 255;
        WT[n * IC + k] = f2b(W[g]);
    }
}

// ---------------- scale: xb[n] = bf16(x[n] * rsqrt(deg[n])) ----------------
// Pre-scaling by the SOURCE-side dinv removes the per-edge random dinv[r]
// load (and one dependency hop) from the latency-bound gather.
__global__ __launch_bounds__(256) void k_scale(
        const unsigned long long* __restrict__ deg64,
        const float* __restrict__ x,
        unsigned short* __restrict__ xb) {
    int t = threadIdx.x;
    int n = blockIdx.x * 16 + (t >> 4);       // n < 50000 always (3125*16 exact)
    int l = t & 15;
    float di = deg_to_di(deg64[n]);
    const float4* xr = (const float4*)(x + (size_t)n * IC + l * 8);
    float4 a0 = xr[0], a1 = xr[1];
    bf16x8 o;
    o[0] = (short)f2b(a0.x * di); o[1] = (short)f2b(a0.y * di);
    o[2] = (short)f2b(a0.z * di); o[3] = (short)f2b(a0.w * di);
    o[4] = (short)f2b(a1.x * di); o[5] = (short)f2b(a1.y * di);
    o[6] = (short)f2b(a1.z * di); o[7] = (short)f2b(a1.w * di);
    ((bf16x8*)xb)[(size_t)n * 16 + l] = o;
}

// ---------------- fused gather + GEMM (r4-proven shape; best measured) ----------------
// 32 nodes per block, 8 lanes per node. uint4 descriptor prefetch one group
// ahead + unroll-4 -> 8 independent 16B row loads in flight per lane,
// descriptors always ready before row-load issue (VMEM completes in order).
// At the scattered-sector wall: ~2.3M 64B sectors @ ~50G/s chip-wide
// (tier-insensitive; measured across 9 structural variants r1-r9).
// Phase B: 4 waves, each 32m x 64n MFMA tile, K=128.
__global__ __launch_bounds__(256) void k_gather_gemm(
        const unsigned short* __restrict__ xb,
        const unsigned long long* __restrict__ deg64,
        const unsigned* __restrict__ epack,
        const unsigned short* __restrict__ WT,
        const float* __restrict__ bias,
        float* __restrict__ out) {
    __shared__ __align__(16) unsigned short a[32][136];   // 272B stride: 2-way alias only (free)

    const int base = blockIdx.x * 32;
    const int g = threadIdx.x >> 3;           // node group 0..31
    const int l8 = threadIdx.x & 7;           // owns segments l8 and l8+8 (8 bf16 each)
    const int n = base + g;
    const bf16x8* xv = (const bf16x8*)xb;     // row = 16 units of 8 bf16

    float acc[16];
    if (n < NN) {
        unsigned long long dv = deg64[n];
        float di = deg_to_di(dv);
        int cnt = (int)(dv >> 32);
        if (cnt > CAP) cnt = CAP;

        // self term: xb[n] = x[n]*di, want x[n]*di^2 -> scale by di
        bf16x8 xs0 = xv[(size_t)n * 16 + l8];
        bf16x8 xs1 = xv[(size_t)n * 16 + 8 + l8];
        #pragma unroll
        for (int c = 0; c < 8; ++c) { acc[c] = b2f(xs0[c]) * di; acc[8 + c] = b2f(xs1[c]) * di; }

        const unsigned* ep = epack + (size_t)n * CAP;
        uint4 q = *(const uint4*)ep;          // descriptors for group 0
        int e = 0;
        for (; e + 4 <= cnt; e += 4) {
            uint4 cur = q;
            q = *(const uint4*)(ep + e + 4);  // prefetch next group (overread safe: pad)
            int r0 = (int)(cur.x & 0xFFFFu);
            int r1 = (int)(cur.y & 0xFFFFu);
            int r2 = (int)(cur.z & 0xFFFFu);
            int r3 = (int)(cur.w & 0xFFFFu);
            float w0 = h2f((unsigned short)(cur.x >> 16)) * di;
            float w1 = h2f((unsigned short)(cur.y >> 16)) * di;
            float w2 = h2f((unsigned short)(cur.z >> 16)) * di;
            float w3 = h2f((unsigned short)(cur.w >> 16)) * di;
            bf16x8 v00 = xv[(size_t)r0 * 16 + l8];
            bf16x8 v01 = xv[(size_t)r0 * 16 + 8 + l8];
            bf16x8 v10 = xv[(size_t)r1 * 16 + l8];
            bf16x8 v11 = xv[(size_t)r1 * 16 + 8 + l8];
            bf16x8 v20 = xv[(size_t)r2 * 16 + l8];
            bf16x8 v21 = xv[(size_t)r2 * 16 + 8 + l8];
            bf16x8 v30 = xv[(size_t)r3 * 16 + l8];
            bf16x8 v31 = xv[(size_t)r3 * 16 + 8 + l8];
            #pragma unroll
            for (int c = 0; c < 8; ++c) { acc[c] += b2f(v00[c]) * w0; acc[8 + c] += b2f(v01[c]) * w0; }
            #pragma unroll
            for (int c = 0; c < 8; ++c) { acc[c] += b2f(v10[c]) * w1; acc[8 + c] += b2f(v11[c]) * w1; }
            #pragma unroll
            for (int c = 0; c < 8; ++c) { acc[c] += b2f(v20[c]) * w2; acc[8 + c] += b2f(v21[c]) * w2; }
            #pragma unroll
            for (int c = 0; c < 8; ++c) { acc[c] += b2f(v30[c]) * w3; acc[8 + c] += b2f(v31[c]) * w3; }
        }
        for (; e < cnt; ++e) {                // tail 0-3 edges, lines already hot
            unsigned p = ep[e];
            int r = (int)(p & 0xFFFFu);
            float w = h2f((unsigned short)(p >> 16)) * di;
            bf16x8 v0 = xv[(size_t)r * 16 + l8];
            bf16x8 v1 = xv[(size_t)r * 16 + 8 + l8];
            #pragma unroll
            for (int c = 0; c < 8; ++c) { acc[c] += b2f(v0[c]) * w; acc[8 + c] += b2f(v1[c]) * w; }
        }
    } else {
        #pragma unroll
        for (int c = 0; c < 16; ++c) acc[c] = 0.0f;
    }

    bf16x8 o0, o1;
    #pragma unroll
    for (int c = 0; c < 8; ++c) { o0[c] = (short)f2b(acc[c]); o1[c] = (short)f2b(acc[8 + c]); }
    *(bf16x8*)(&a[g][l8 * 8]) = o0;
    *(bf16x8*)(&a[g][64 + l8 * 8]) = o1;

    __syncthreads();

    // --- Phase B: GEMM  out[32m x 256n] = a @ WT^T + bias ---
    const int w = threadIdx.x >> 6;           // wave 0..3 -> n-quadrant
    const int lane = threadIdx.x & 63;
    const int n0 = w * 64;
    const int lm = lane & 15;
    const int lk = (lane >> 4) * 8;

    f32x4 acc4[2][4] = {};
    #pragma unroll
    for (int ks = 0; ks < 4; ++ks) {
        const int k0 = ks * 32 + lk;
        bf16x8 wf[4], af[2];
        #pragma unroll
        for (int j = 0; j < 4; ++j)
            wf[j] = *(const bf16x8*)(WT + (size_t)(n0 + j * 16 + lm) * IC + k0);
        #pragma unroll
        for (int i = 0; i < 2; ++i)
            af[i] = *(const bf16x8*)(&a[i * 16 + lm][k0]);
        #pragma unroll
        for (int i = 0; i < 2; ++i)
            #pragma unroll
            for (int j = 0; j < 4; ++j)
                acc4[i][j] = __builtin_amdgcn_mfma_f32_16x16x32_bf16(wf[j], af[i], acc4[i][j], 0, 0, 0);
    }

    // swapped D layout: col(lane&15) = m-dim, row((lane>>4)*4+reg) = n-dim
    const int mcol = lane & 15;
    const int nb4 = (lane >> 4) * 4;
    #pragma unroll
    for (int i = 0; i < 2; ++i) {
        int m = base + i * 16 + mcol;
        if (m < NN) {
            #pragma unroll
            for (int j = 0; j < 4; ++j) {
                int nn = n0 + j * 16 + nb4;
                float4 bv = *(const float4*)&bias[nn];
                float4 ov;
                ov.x = acc4[i][j][0] + bv.x;
                ov.y = acc4[i][j][1] + bv.y;
                ov.z = acc4[i][j][2] + bv.z;
                ov.w = acc4[i][j][3] + bv.w;
                *(float4*)(out + (size_t)m * OC + nn) = ov;
            }
        }
    }
}

// ---------------- launch ----------------
extern "C" void kernel_launch(void* const* d_in, const int* in_sizes, int n_in,
                              void* d_out, int out_size, void* d_ws, size_t ws_size,
                              hipStream_t stream) {
    const float* x  = (const float*)d_in[0];
    const float* W  = (const float*)d_in[1];
    const float* b  = (const float*)d_in[2];
    const int*   ei = (const int*)d_in[3];
    const float* ew = (const float*)d_in[4];
    const int* row = ei;            // source
    const int* col = ei + NE;       // target
    float* out = (float*)d_out;

    char* w0 = (char*)d_ws;
    unsigned long long* deg64 = (unsigned long long*)w0;  w0 += NPAD * 8;
    unsigned* epack = (unsigned*)w0;             w0 += ((size_t)NPAD * CAP + 128) * 4;  // 12.9 MB + pad
    unsigned short* WT   = (unsigned short*)w0;  w0 += IC * OC * 2;
    unsigned short* xb   = (unsigned short*)w0;  // NN*IC bf16 = 12.8 MB (pre-scaled by dinv)

    hipMemsetAsync(deg64, 0, NPAD * 8, stream);   // deg = self-loop-excluded 0; +1.0 in decode
    k_pass1      <<<NEB, 256, 0, stream>>>(row, col, ew, deg64, epack, W, WT);
    k_scale      <<<NN / 16, 256, 0, stream>>>(deg64, x, xb);
    k_gather_gemm<<<(NN + 31) / 32, 256, 0, stream>>>(xb, deg64, epack, WT, b, out);
}